// Round 1
// baseline (7319.530 us; speedup 1.0000x reference)
//
#include <hip/hip_runtime.h>

// ---------------------------------------------------------------------------
// HypergraphNet: out = conv2(relu(conv1(x)))
// conv(x) = D^-1 H diag(w) B^-1 H^T (x @ W) + b
// N = E = 65536, F = 128, nnz = 2^20, all fp32.
//
// Round-0 structure:
//   k_degrees   : atomic histogram of deg_n (sum w) and deg_e (count)  [once]
//   k_scales    : d_inv = 1/deg_n, e_scale = w/deg_e                   [once]
//   k_gemm      : fp32 tiled 128x128 SGEMM (no fp32 MFMA on CDNA4)
//   k_scatter   : gather 512B row, scale, 128x atomicAdd scatter
//   k_epilogue  : y = x*d_inv[row] + b[col] (+relu)
// ---------------------------------------------------------------------------

__global__ __launch_bounds__(256) void k_degrees(const int* __restrict__ nidx,
                                                 const int* __restrict__ eidx,
                                                 const float* __restrict__ w,
                                                 float* __restrict__ deg_n,
                                                 float* __restrict__ deg_e,
                                                 int nnz) {
  int i = blockIdx.x * 256 + threadIdx.x;
  if (i < nnz) {
    int n = nidx[i], e = eidx[i];
    unsafeAtomicAdd(&deg_n[n], w[e]);
    unsafeAtomicAdd(&deg_e[e], 1.0f);
  }
}

__global__ __launch_bounds__(256) void k_scales(const float* __restrict__ w,
                                                const float* __restrict__ deg_n,
                                                const float* __restrict__ deg_e,
                                                float* __restrict__ d_inv,
                                                float* __restrict__ e_scale,
                                                int N, int E) {
  int i = blockIdx.x * 256 + threadIdx.x;
  if (i < N) { float d = deg_n[i]; d_inv[i]  = d > 0.f ? 1.f / d : 0.f; }
  if (i < E) { float d = deg_e[i]; e_scale[i] = d > 0.f ? w[i] / d : 0.f; }
}

// C[M,128] = A[M,128] @ B[128,128], fp32, one block per 128 rows.
// 256 threads, 8x8 micro-tile each, K chunked by 32 through LDS.
__global__ __launch_bounds__(256) void k_gemm(const float* __restrict__ A,
                                              const float* __restrict__ B,
                                              float* __restrict__ C) {
  __shared__ float As[32][128];  // [k][m] (transposed on store)
  __shared__ float Bs[32][128];  // [k][n]
  const int tid = threadIdx.x;
  const int tx = tid & 15;   // n
  const int ty = tid >> 4;   // m
  const size_t m0 = (size_t)blockIdx.x * 128;

  float acc[8][8];
#pragma unroll
  for (int i = 0; i < 8; ++i)
#pragma unroll
    for (int j = 0; j < 8; ++j) acc[i][j] = 0.f;

  const int lm = tid >> 1;          // A row within tile
  const int lk = (tid & 1) * 16;    // A k offset
  const int bk = tid >> 3;          // B row within chunk
  const int bn = (tid & 7) * 16;    // B col offset

  for (int k0 = 0; k0 < 128; k0 += 32) {
    float4 a[4], b[4];
    const float4* ap = reinterpret_cast<const float4*>(A + (m0 + lm) * 128 + k0 + lk);
#pragma unroll
    for (int j = 0; j < 4; ++j) a[j] = ap[j];
    const float4* bp = reinterpret_cast<const float4*>(B + (size_t)(k0 + bk) * 128 + bn);
#pragma unroll
    for (int j = 0; j < 4; ++j) b[j] = bp[j];

    __syncthreads();
#pragma unroll
    for (int j = 0; j < 4; ++j) {
      As[lk + 4 * j + 0][lm] = a[j].x;
      As[lk + 4 * j + 1][lm] = a[j].y;
      As[lk + 4 * j + 2][lm] = a[j].z;
      As[lk + 4 * j + 3][lm] = a[j].w;
      reinterpret_cast<float4*>(&Bs[bk][bn])[j] = b[j];
    }
    __syncthreads();

#pragma unroll
    for (int kk = 0; kk < 32; ++kk) {
      const float4* ar = reinterpret_cast<const float4*>(&As[kk][ty * 8]);
      const float4* br = reinterpret_cast<const float4*>(&Bs[kk][tx * 8]);
      float4 a0 = ar[0], a1 = ar[1];
      float4 b0 = br[0], b1 = br[1];
      float af[8] = {a0.x, a0.y, a0.z, a0.w, a1.x, a1.y, a1.z, a1.w};
      float bf[8] = {b0.x, b0.y, b0.z, b0.w, b1.x, b1.y, b1.z, b1.w};
#pragma unroll
      for (int i = 0; i < 8; ++i)
#pragma unroll
        for (int j = 0; j < 8; ++j) acc[i][j] = fmaf(af[i], bf[j], acc[i][j]);
    }
  }

#pragma unroll
  for (int i = 0; i < 8; ++i) {
    float4 c0 = make_float4(acc[i][0], acc[i][1], acc[i][2], acc[i][3]);
    float4 c1 = make_float4(acc[i][4], acc[i][5], acc[i][6], acc[i][7]);
    float4* cp = reinterpret_cast<float4*>(C + (m0 + ty * 8 + i) * 128 + tx * 8);
    cp[0] = c0;
    cp[1] = c1;
  }
}

// One nnz entry per half-wave (32 lanes x float4 = 512B row).
// dst[sidx[e]] += src[gidx[e]] * (e_scale ? e_scale[gidx[e]] : 1)
__global__ __launch_bounds__(256) void k_scatter(const float4* __restrict__ src,
                                                 float* __restrict__ dst,
                                                 const int* __restrict__ gidx,
                                                 const int* __restrict__ sidx,
                                                 const float* __restrict__ e_scale,
                                                 int nnz) {
  int t = blockIdx.x * 256 + threadIdx.x;
  int entry = t >> 5;
  int lane = t & 31;
  if (entry >= nnz) return;
  int g = gidx[entry];
  int s = sidx[entry];
  float sc = e_scale ? e_scale[g] : 1.0f;
  float4 v = src[(size_t)g * 32 + lane];
  float* d = dst + (size_t)s * 128 + lane * 4;
  unsafeAtomicAdd(d + 0, v.x * sc);
  unsafeAtomicAdd(d + 1, v.y * sc);
  unsafeAtomicAdd(d + 2, v.z * sc);
  unsafeAtomicAdd(d + 3, v.w * sc);
}

__global__ __launch_bounds__(256) void k_epilogue(const float4* __restrict__ in,
                                                  float4* __restrict__ out,
                                                  const float* __restrict__ d_inv,
                                                  const float4* __restrict__ bias,
                                                  int do_relu, int n4) {
  int i = blockIdx.x * 256 + threadIdx.x;
  if (i >= n4) return;
  int row = i >> 5;   // 32 float4 per 128-wide row
  int c4 = i & 31;
  float4 v = in[i];
  float di = d_inv[row];
  float4 b = bias[c4];
  v.x = v.x * di + b.x;
  v.y = v.y * di + b.y;
  v.z = v.z * di + b.z;
  v.w = v.w * di + b.w;
  if (do_relu) {
    v.x = fmaxf(v.x, 0.f);
    v.y = fmaxf(v.y, 0.f);
    v.z = fmaxf(v.z, 0.f);
    v.w = fmaxf(v.w, 0.f);
  }
  out[i] = v;
}

extern "C" void kernel_launch(void* const* d_in, const int* in_sizes, int n_in,
                              void* d_out, int out_size, void* d_ws, size_t ws_size,
                              hipStream_t stream) {
  const float* x  = (const float*)d_in[0];
  const int* nidx = (const int*)d_in[1];
  const int nnz   = in_sizes[1] / 2;
  const int* eidx = nidx + nnz;
  const float* w  = (const float*)d_in[2];
  const float* W1 = (const float*)d_in[3];
  const float* b1 = (const float*)d_in[4];
  const float* W2 = (const float*)d_in[5];
  const float* b2 = (const float*)d_in[6];
  float* out = (float*)d_out;

  const int N = in_sizes[0] / 128;  // 65536 nodes
  const int E = in_sizes[2];        // 65536 edges
  const size_t NB = (size_t)N * 128;

  float* f0      = (float*)d_ws;        // [N,128]
  float* f1      = f0 + NB;             // [N,128]
  float* deg_n   = f1 + NB;             // [N]
  float* deg_e   = deg_n + N;           // [E]
  float* d_inv   = deg_e + E;           // [N]
  float* e_scale = d_inv + N;           // [E]

  const int NE = (N > E) ? N : E;
  const int gemm_grid = N / 128;
  const int sc_grid = (int)(((size_t)nnz * 32 + 255) / 256);
  const int ep_grid = (int)((NB / 4 + 255) / 256);

  // degrees + scales (shared by both layers)
  hipMemsetAsync(deg_n, 0, (size_t)(N + E) * sizeof(float), stream);
  k_degrees<<<(nnz + 255) / 256, 256, 0, stream>>>(nidx, eidx, w, deg_n, deg_e, nnz);
  k_scales<<<(NE + 255) / 256, 256, 0, stream>>>(w, deg_n, deg_e, d_inv, e_scale, N, E);

  // ---- layer 1 ----
  k_gemm<<<gemm_grid, 256, 0, stream>>>(x, W1, f0);                      // f0 = x@W1
  hipMemsetAsync(f1, 0, NB * sizeof(float), stream);
  k_scatter<<<sc_grid, 256, 0, stream>>>((const float4*)f0, f1, nidx, eidx, nullptr, nnz);   // e = H^T f0
  hipMemsetAsync(out, 0, NB * sizeof(float), stream);
  k_scatter<<<sc_grid, 256, 0, stream>>>((const float4*)f1, out, eidx, nidx, e_scale, nnz);  // t = H w B^-1 e
  k_epilogue<<<ep_grid, 256, 0, stream>>>((const float4*)out, (float4*)f0, d_inv,
                                          (const float4*)b1, 1, (int)(NB / 4));              // f0 = relu(t*Dinv+b1)

  // ---- layer 2 ----
  k_gemm<<<gemm_grid, 256, 0, stream>>>(f0, W2, f1);                     // f1 = h@W2
  hipMemsetAsync(f0, 0, NB * sizeof(float), stream);
  k_scatter<<<sc_grid, 256, 0, stream>>>((const float4*)f1, f0, nidx, eidx, nullptr, nnz);
  hipMemsetAsync(out, 0, NB * sizeof(float), stream);
  k_scatter<<<sc_grid, 256, 0, stream>>>((const float4*)f0, out, eidx, nidx, e_scale, nnz);
  k_epilogue<<<ep_grid, 256, 0, stream>>>((const float4*)out, (float4*)out, d_inv,
                                          (const float4*)b2, 0, (int)(NB / 4));
}

// Round 2
// 882.760 us; speedup vs baseline: 8.2916x; 8.2916x over previous
//
#include <hip/hip_runtime.h>

// ---------------------------------------------------------------------------
// HypergraphNet: out = conv2(relu(conv1(x)))
// conv(x) = D^-1 H diag(w) B^-1 H^T (x @ W) + b
// N = E = 65536, F = 128, nnz = 2^20, all fp32.
//
// Round-1 structure: atomics eliminated from the feature passes.
//   k_count  : int histograms cnt_e/cnt_n (CSR counts) + float deg_n (sum w)
//   k_scales : d_inv = 1/deg_n (in place), e_scale = w/cnt_e
//   k_scan   : exclusive prefix sum -> rp_e / rp_n (one block each)
//   k_fill   : scatter entry "other" index into CSR col arrays (ushort)
//   k_gemm   : fp32 tiled 128x128 SGEMM (no fp32 MFMA on CDNA4)
//   k_gather : one wave per output row; register accumulate; fused
//              row-scale (+bias+relu on the node-side pass). NO atomics.
// ---------------------------------------------------------------------------

__global__ __launch_bounds__(256) void k_count(const int* __restrict__ nidx,
                                               const int* __restrict__ eidx,
                                               const float* __restrict__ w,
                                               int* __restrict__ cnt_e,
                                               int* __restrict__ cnt_n,
                                               float* __restrict__ deg_n,
                                               int nnz) {
  int i = blockIdx.x * 256 + threadIdx.x;
  if (i < nnz) {
    int n = nidx[i], e = eidx[i];
    atomicAdd(&cnt_e[e], 1);
    atomicAdd(&cnt_n[n], 1);
    unsafeAtomicAdd(&deg_n[n], w[e]);
  }
}

__global__ __launch_bounds__(256) void k_scales(const float* __restrict__ w,
                                                const int* __restrict__ cnt_e,
                                                float* __restrict__ d_inv,   // in: deg_n
                                                float* __restrict__ e_scale,
                                                int N, int E) {
  int i = blockIdx.x * 256 + threadIdx.x;
  if (i < N) { float d = d_inv[i]; d_inv[i] = d > 0.f ? 1.f / d : 0.f; }
  if (i < E) { int c = cnt_e[i]; e_scale[i] = c > 0 ? w[i] / (float)c : 0.f; }
}

// Exclusive scan of a 65536-int array; one 1024-thread block per array.
__global__ __launch_bounds__(1024) void k_scan(const int* __restrict__ cnt_e,
                                               int* __restrict__ rp_e, int En,
                                               const int* __restrict__ cnt_n,
                                               int* __restrict__ rp_n, int Nn) {
  const int* cnt = (blockIdx.x == 0) ? cnt_e : cnt_n;
  int* rp = (blockIdx.x == 0) ? rp_e : rp_n;
  int n = (blockIdx.x == 0) ? En : Nn;
  __shared__ int sums[1024];
  const int tid = threadIdx.x;
  const int per = n >> 10;  // 64
  const int base = tid * per;
  int s = 0;
  for (int j = 0; j < per; ++j) s += cnt[base + j];
  sums[tid] = s;
  __syncthreads();
  for (int off = 1; off < 1024; off <<= 1) {
    int v = (tid >= off) ? sums[tid - off] : 0;
    __syncthreads();
    if (tid >= off) sums[tid] += v;
    __syncthreads();
  }
  int excl = (tid == 0) ? 0 : sums[tid - 1];
  for (int j = 0; j < per; ++j) {
    rp[base + j] = excl;
    excl += cnt[base + j];
  }
  if (tid == 1023) rp[n] = excl;
}

__global__ __launch_bounds__(256) void k_fill(const int* __restrict__ nidx,
                                              const int* __restrict__ eidx,
                                              int* __restrict__ cur_e,
                                              int* __restrict__ cur_n,
                                              unsigned short* __restrict__ col_e,
                                              unsigned short* __restrict__ col_n,
                                              int nnz) {
  int i = blockIdx.x * 256 + threadIdx.x;
  if (i < nnz) {
    int n = nidx[i], e = eidx[i];
    int pe = atomicAdd(&cur_e[e], 1);
    col_e[pe] = (unsigned short)n;
    int pn = atomicAdd(&cur_n[n], 1);
    col_n[pn] = (unsigned short)e;
  }
}

// C[M,128] = A[M,128] @ B[128,128], fp32, one block per 128 rows.
__global__ __launch_bounds__(256) void k_gemm(const float* __restrict__ A,
                                              const float* __restrict__ B,
                                              float* __restrict__ C) {
  __shared__ float As[32][128];  // [k][m]
  __shared__ float Bs[32][128];  // [k][n]
  const int tid = threadIdx.x;
  const int tx = tid & 15;   // n
  const int ty = tid >> 4;   // m
  const size_t m0 = (size_t)blockIdx.x * 128;

  float acc[8][8];
#pragma unroll
  for (int i = 0; i < 8; ++i)
#pragma unroll
    for (int j = 0; j < 8; ++j) acc[i][j] = 0.f;

  const int lm = tid >> 1;
  const int lk = (tid & 1) * 16;
  const int bk = tid >> 3;
  const int bn = (tid & 7) * 16;

  for (int k0 = 0; k0 < 128; k0 += 32) {
    float4 a[4], b[4];
    const float4* ap = reinterpret_cast<const float4*>(A + (m0 + lm) * 128 + k0 + lk);
#pragma unroll
    for (int j = 0; j < 4; ++j) a[j] = ap[j];
    const float4* bp = reinterpret_cast<const float4*>(B + (size_t)(k0 + bk) * 128 + bn);
#pragma unroll
    for (int j = 0; j < 4; ++j) b[j] = bp[j];

    __syncthreads();
#pragma unroll
    for (int j = 0; j < 4; ++j) {
      As[lk + 4 * j + 0][lm] = a[j].x;
      As[lk + 4 * j + 1][lm] = a[j].y;
      As[lk + 4 * j + 2][lm] = a[j].z;
      As[lk + 4 * j + 3][lm] = a[j].w;
      reinterpret_cast<float4*>(&Bs[bk][bn])[j] = b[j];
    }
    __syncthreads();

#pragma unroll
    for (int kk = 0; kk < 32; ++kk) {
      const float4* ar = reinterpret_cast<const float4*>(&As[kk][ty * 8]);
      const float4* br = reinterpret_cast<const float4*>(&Bs[kk][tx * 8]);
      float4 a0 = ar[0], a1 = ar[1];
      float4 b0 = br[0], b1 = br[1];
      float af[8] = {a0.x, a0.y, a0.z, a0.w, a1.x, a1.y, a1.z, a1.w};
      float bf[8] = {b0.x, b0.y, b0.z, b0.w, b1.x, b1.y, b1.z, b1.w};
#pragma unroll
      for (int i = 0; i < 8; ++i)
#pragma unroll
        for (int j = 0; j < 8; ++j) acc[i][j] = fmaf(af[i], bf[j], acc[i][j]);
    }
  }

#pragma unroll
  for (int i = 0; i < 8; ++i) {
    float4 c0 = make_float4(acc[i][0], acc[i][1], acc[i][2], acc[i][3]);
    float4 c1 = make_float4(acc[i][4], acc[i][5], acc[i][6], acc[i][7]);
    float4* cp = reinterpret_cast<float4*>(C + (m0 + ty * 8 + i) * 128 + tx * 8);
    cp[0] = c0;
    cp[1] = c1;
  }
}

// One wave (64 lanes x float2) per output row.
// dst[row] = (sum_{j in [rp[row],rp[row+1])} src[col[j]]) * rscale[row] (+bias, relu)
__global__ __launch_bounds__(256) void k_gather(const float2* __restrict__ src,
                                                float2* __restrict__ dst,
                                                const int* __restrict__ rp,
                                                const unsigned short* __restrict__ col,
                                                const float* __restrict__ rscale,
                                                const float2* __restrict__ bias,
                                                int relu, int nrows) {
  const int row = (blockIdx.x * 256 + threadIdx.x) >> 6;
  const int lane = threadIdx.x & 63;
  if (row >= nrows) return;
  const int beg = rp[row], end = rp[row + 1];
  float2 acc = {0.f, 0.f};
  int j = beg;
  for (; j + 1 < end; j += 2) {   // unroll-2: two loads in flight
    int c0 = col[j], c1 = col[j + 1];
    float2 v0 = src[(size_t)c0 * 64 + lane];
    float2 v1 = src[(size_t)c1 * 64 + lane];
    acc.x += v0.x + v1.x;
    acc.y += v0.y + v1.y;
  }
  if (j < end) {
    int c = col[j];
    float2 v = src[(size_t)c * 64 + lane];
    acc.x += v.x;
    acc.y += v.y;
  }
  const float s = rscale[row];
  acc.x *= s;
  acc.y *= s;
  if (bias) {
    float2 b = bias[lane];
    acc.x += b.x;
    acc.y += b.y;
    if (relu) { acc.x = fmaxf(acc.x, 0.f); acc.y = fmaxf(acc.y, 0.f); }
  }
  dst[(size_t)row * 64 + lane] = acc;
}

extern "C" void kernel_launch(void* const* d_in, const int* in_sizes, int n_in,
                              void* d_out, int out_size, void* d_ws, size_t ws_size,
                              hipStream_t stream) {
  const float* x  = (const float*)d_in[0];
  const int* nidx = (const int*)d_in[1];
  const int nnz   = in_sizes[1] / 2;
  const int* eidx = nidx + nnz;
  const float* w  = (const float*)d_in[2];
  const float* W1 = (const float*)d_in[3];
  const float* b1 = (const float*)d_in[4];
  const float* W2 = (const float*)d_in[5];
  const float* b2 = (const float*)d_in[6];
  float* out = (float*)d_out;

  const int N = in_sizes[0] / 128;  // 65536 nodes
  const int E = in_sizes[2];        // 65536 edges
  const size_t NB = (size_t)N * 128;

  // workspace layout (4-byte units)
  float* f0      = (float*)d_ws;            // [N,128]
  float* f1      = f0 + NB;                 // [N,128]
  float* deg_n   = f1 + NB;                 // [N]  -> becomes d_inv in place
  float* e_scale = deg_n + N;               // [E]
  int* cnt_e     = (int*)(e_scale + E);     // [E]  (also fill cursor)
  int* cnt_n     = cnt_e + E;               // [N]  (also fill cursor)
  int* rp_e      = cnt_n + N;               // [E+1]
  int* rp_n      = rp_e + E + 1;            // [N+1]
  unsigned short* col_e = (unsigned short*)(rp_n + N + 1);  // [nnz]
  unsigned short* col_n = col_e + nnz;                      // [nnz]
  float* d_inv = deg_n;

  const int gemm_grid = N / 128;
  const int ga_grid_e = (E * 64) / 256;
  const int ga_grid_n = (N * 64) / 256;

  // ---- CSR build + scales (shared by both layers) ----
  hipMemsetAsync(deg_n, 0, (size_t)N * sizeof(float), stream);
  hipMemsetAsync(cnt_e, 0, (size_t)(E + N) * sizeof(int), stream);
  k_count<<<(nnz + 255) / 256, 256, 0, stream>>>(nidx, eidx, w, cnt_e, cnt_n, deg_n, nnz);
  k_scales<<<(N + 255) / 256, 256, 0, stream>>>(w, cnt_e, d_inv, e_scale, N, E);
  k_scan<<<2, 1024, 0, stream>>>(cnt_e, rp_e, E, cnt_n, rp_n, N);
  hipMemcpyAsync(cnt_e, rp_e, (size_t)E * sizeof(int), hipMemcpyDeviceToDevice, stream);
  hipMemcpyAsync(cnt_n, rp_n, (size_t)N * sizeof(int), hipMemcpyDeviceToDevice, stream);
  k_fill<<<(nnz + 255) / 256, 256, 0, stream>>>(nidx, eidx, cnt_e, cnt_n, col_e, col_n, nnz);

  // ---- layer 1 ----
  k_gemm<<<gemm_grid, 256, 0, stream>>>(x, W1, f0);  // f0 = x@W1
  k_gather<<<ga_grid_e, 256, 0, stream>>>((const float2*)f0, (float2*)f1, rp_e, col_e,
                                          e_scale, nullptr, 0, E);           // f1 = e_feat
  k_gather<<<ga_grid_n, 256, 0, stream>>>((const float2*)f1, (float2*)f0, rp_n, col_n,
                                          d_inv, (const float2*)b1, 1, N);   // f0 = h

  // ---- layer 2 ----
  k_gemm<<<gemm_grid, 256, 0, stream>>>(f0, W2, f1);  // f1 = h@W2
  k_gather<<<ga_grid_e, 256, 0, stream>>>((const float2*)f1, (float2*)f0, rp_e, col_e,
                                          e_scale, nullptr, 0, E);           // f0 = e_feat
  k_gather<<<ga_grid_n, 256, 0, stream>>>((const float2*)f0, (float2*)out, rp_n, col_n,
                                          d_inv, (const float2*)b2, 0, N);   // out
}

// Round 3
// 509.362 us; speedup vs baseline: 14.3700x; 1.7331x over previous
//
#include <hip/hip_runtime.h>

// ---------------------------------------------------------------------------
// HypergraphNet: out = conv2(relu(conv1(x)))
// conv(x) = D^-1 H diag(w) B^-1 H^T (x @ W) + b
// N = E = 65536, F = 128, nnz = 2^20, all fp32.
//
// Round-2: CSR build rewritten as 2-level binned counting sort (no global
// scatter of small values; write amplification ~2x instead of ~39x).
//   k_passA      : LDS-private coarse histogram (key>>8), 256 bins/side
//   k_coarse_scan: scan coarse bins -> bucket bases + cursors
//   k_passB      : block-local binning; one global atomic per digit per
//                  block; dense 4B-record chunk writes
//   k_passC      : per-bucket finalize: rp, e_scale / d_inv (deg via LDS
//                  float atomics), col (ushort) -- all within an 8KB
//                  single-XCD-resident region
//   k_gemm       : fp32 tiled 128x128 SGEMM (no fp32 MFMA on CDNA4)
//   k_gather     : 32 lanes x float4 per row, unroll-4, fused scale/bias/relu
// ---------------------------------------------------------------------------

typedef unsigned int uint32;
typedef unsigned short ushort16;

__global__ __launch_bounds__(256) void k_passA(const int* __restrict__ nidx,
                                               const int* __restrict__ eidx,
                                               int* __restrict__ coarse_e,
                                               int* __restrict__ coarse_n,
                                               int nnz) {
  __shared__ int he[256], hn[256];
  const int tid = threadIdx.x;
  he[tid] = 0;
  hn[tid] = 0;
  __syncthreads();
  const int base = blockIdx.x * 4096;
#pragma unroll
  for (int it = 0; it < 16; ++it) {
    int i = base + it * 256 + tid;
    if (i < nnz) {
      atomicAdd(&he[eidx[i] >> 8], 1);
      atomicAdd(&hn[nidx[i] >> 8], 1);
    }
  }
  __syncthreads();
  atomicAdd(&coarse_e[tid], he[tid]);
  atomicAdd(&coarse_n[tid], hn[tid]);
}

// One block. Exclusive-scan both 256-entry coarse count arrays; init cursors.
__global__ __launch_bounds__(256) void k_coarse_scan(const int* __restrict__ ce,
                                                     int* __restrict__ be,
                                                     int* __restrict__ cure,
                                                     const int* __restrict__ cn,
                                                     int* __restrict__ bn,
                                                     int* __restrict__ curn) {
  __shared__ int s[256];
  const int tid = threadIdx.x;
  // e side
  int v = ce[tid];
  s[tid] = v;
  __syncthreads();
  for (int off = 1; off < 256; off <<= 1) {
    int t = (tid >= off) ? s[tid - off] : 0;
    __syncthreads();
    s[tid] += t;
    __syncthreads();
  }
  be[tid] = s[tid] - v;
  cure[tid] = s[tid] - v;
  if (tid == 255) be[256] = s[255];
  __syncthreads();
  // n side
  v = cn[tid];
  s[tid] = v;
  __syncthreads();
  for (int off = 1; off < 256; off <<= 1) {
    int t = (tid >= off) ? s[tid - off] : 0;
    __syncthreads();
    s[tid] += t;
    __syncthreads();
  }
  bn[tid] = s[tid] - v;
  curn[tid] = s[tid] - v;
  if (tid == 255) bn[256] = s[255];
}

// Bin entries into coarse buckets as packed records (keylow<<16 | value).
// blocks 0..255: e-side chunk b; blocks 256..511: n-side chunk b.
__global__ __launch_bounds__(256) void k_passB(const int* __restrict__ nidx,
                                               const int* __restrict__ eidx,
                                               int* __restrict__ cur_e,
                                               int* __restrict__ cur_n,
                                               uint32* __restrict__ rec_e,
                                               uint32* __restrict__ rec_n,
                                               int nnz) {
  __shared__ int hist[256];
  __shared__ int gbase[256];
  __shared__ int lcur[256];
  const int tid = threadIdx.x;
  const int side = blockIdx.x >> 8;
  const int blk = blockIdx.x & 255;
  const int* keyp = side ? nidx : eidx;
  const int* valp = side ? eidx : nidx;
  int* cursor = side ? cur_n : cur_e;
  uint32* rec = side ? rec_n : rec_e;

  hist[tid] = 0;
  __syncthreads();
  int key[16], val[16];
  const int base = blk * 4096;
#pragma unroll
  for (int it = 0; it < 16; ++it) {
    int i = base + it * 256 + tid;
    if (i < nnz) {
      key[it] = keyp[i];
      val[it] = valp[i];
      atomicAdd(&hist[key[it] >> 8], 1);
    } else {
      key[it] = -1;
    }
  }
  __syncthreads();
  gbase[tid] = atomicAdd(&cursor[tid], hist[tid]);
  lcur[tid] = 0;
  __syncthreads();
#pragma unroll
  for (int it = 0; it < 16; ++it) {
    if (key[it] >= 0) {
      int d = key[it] >> 8;
      int p = atomicAdd(&lcur[d], 1);
      rec[gbase[d] + p] = ((uint32)(key[it] & 0xff) << 16) | (uint32)val[it];
    }
  }
}

// Finalize one coarse bucket: rp, scale, col.
// blocks 0..255: e-side (scale = w[key]/cnt); 256..511: n-side (1/sum w[val]).
__global__ __launch_bounds__(256) void k_passC(const uint32* __restrict__ rec_e,
                                               const uint32* __restrict__ rec_n,
                                               const int* __restrict__ be,
                                               const int* __restrict__ bn,
                                               const float* __restrict__ w,
                                               int* __restrict__ rp_e,
                                               int* __restrict__ rp_n,
                                               ushort16* __restrict__ col_e,
                                               ushort16* __restrict__ col_n,
                                               float* __restrict__ e_scale,
                                               float* __restrict__ d_inv) {
  __shared__ int hist[256];
  __shared__ int s[256];
  __shared__ int lcur[256];
  __shared__ float degf[256];
  const int tid = threadIdx.x;
  const int side = blockIdx.x >> 8;
  const int b = blockIdx.x & 255;
  const uint32* rec = side ? rec_n : rec_e;
  const int* bb = side ? bn : be;
  int* rp = side ? rp_n : rp_e;
  ushort16* col = side ? col_n : col_e;

  const int beg = bb[b], end = bb[b + 1];
  hist[tid] = 0;
  degf[tid] = 0.f;
  __syncthreads();
  for (int j = beg + tid; j < end; j += 256) {
    uint32 r = rec[j];
    int d = r >> 16;
    atomicAdd(&hist[d], 1);
    if (side) atomicAdd(&degf[d], w[r & 0xffff]);
  }
  __syncthreads();
  int h = hist[tid];
  s[tid] = h;
  __syncthreads();
  for (int off = 1; off < 256; off <<= 1) {
    int t = (tid >= off) ? s[tid - off] : 0;
    __syncthreads();
    s[tid] += t;
    __syncthreads();
  }
  const int start = s[tid] - h;  // exclusive within bucket
  const int key = (b << 8) | tid;
  rp[key] = beg + start;
  if (tid == 255) rp[(b << 8) + 256] = end;
  if (side) {
    float d = degf[tid];
    d_inv[key] = d > 0.f ? 1.f / d : 0.f;
  } else {
    e_scale[key] = h > 0 ? w[key] / (float)h : 0.f;
  }
  lcur[tid] = start;
  __syncthreads();
  for (int j = beg + tid; j < end; j += 256) {
    uint32 r = rec[j];
    int d = r >> 16;
    int p = atomicAdd(&lcur[d], 1);
    col[beg + p] = (ushort16)(r & 0xffff);
  }
}

// C[M,128] = A[M,128] @ B[128,128], fp32, one block per 128 rows.
__global__ __launch_bounds__(256) void k_gemm(const float* __restrict__ A,
                                              const float* __restrict__ B,
                                              float* __restrict__ C) {
  __shared__ float As[32][128];  // [k][m]
  __shared__ float Bs[32][128];  // [k][n]
  const int tid = threadIdx.x;
  const int tx = tid & 15;   // n
  const int ty = tid >> 4;   // m
  const size_t m0 = (size_t)blockIdx.x * 128;

  float acc[8][8];
#pragma unroll
  for (int i = 0; i < 8; ++i)
#pragma unroll
    for (int j = 0; j < 8; ++j) acc[i][j] = 0.f;

  const int lm = tid >> 1;
  const int lk = (tid & 1) * 16;
  const int bk = tid >> 3;
  const int bn = (tid & 7) * 16;

  for (int k0 = 0; k0 < 128; k0 += 32) {
    float4 a[4], b[4];
    const float4* ap = reinterpret_cast<const float4*>(A + (m0 + lm) * 128 + k0 + lk);
#pragma unroll
    for (int j = 0; j < 4; ++j) a[j] = ap[j];
    const float4* bp = reinterpret_cast<const float4*>(B + (size_t)(k0 + bk) * 128 + bn);
#pragma unroll
    for (int j = 0; j < 4; ++j) b[j] = bp[j];

    __syncthreads();
#pragma unroll
    for (int j = 0; j < 4; ++j) {
      As[lk + 4 * j + 0][lm] = a[j].x;
      As[lk + 4 * j + 1][lm] = a[j].y;
      As[lk + 4 * j + 2][lm] = a[j].z;
      As[lk + 4 * j + 3][lm] = a[j].w;
      reinterpret_cast<float4*>(&Bs[bk][bn])[j] = b[j];
    }
    __syncthreads();

#pragma unroll
    for (int kk = 0; kk < 32; ++kk) {
      const float4* ar = reinterpret_cast<const float4*>(&As[kk][ty * 8]);
      const float4* br = reinterpret_cast<const float4*>(&Bs[kk][tx * 8]);
      float4 a0 = ar[0], a1 = ar[1];
      float4 b0 = br[0], b1 = br[1];
      float af[8] = {a0.x, a0.y, a0.z, a0.w, a1.x, a1.y, a1.z, a1.w};
      float bf[8] = {b0.x, b0.y, b0.z, b0.w, b1.x, b1.y, b1.z, b1.w};
#pragma unroll
      for (int i = 0; i < 8; ++i)
#pragma unroll
        for (int j = 0; j < 8; ++j) acc[i][j] = fmaf(af[i], bf[j], acc[i][j]);
    }
  }

#pragma unroll
  for (int i = 0; i < 8; ++i) {
    float4 c0 = make_float4(acc[i][0], acc[i][1], acc[i][2], acc[i][3]);
    float4 c1 = make_float4(acc[i][4], acc[i][5], acc[i][6], acc[i][7]);
    float4* cp = reinterpret_cast<float4*>(C + (m0 + ty * 8 + i) * 128 + tx * 8);
    cp[0] = c0;
    cp[1] = c1;
  }
}

// 32 lanes x float4 per output row, unroll-4.
// dst[row] = (sum_j src[col[j]]) * rscale[row] (+bias, relu)
__global__ __launch_bounds__(256) void k_gather(const float4* __restrict__ src,
                                                float4* __restrict__ dst,
                                                const int* __restrict__ rp,
                                                const ushort16* __restrict__ col,
                                                const float* __restrict__ rscale,
                                                const float4* __restrict__ bias,
                                                int relu, int nrows) {
  const int row = (blockIdx.x * 256 + threadIdx.x) >> 5;
  const int lane = threadIdx.x & 31;
  if (row >= nrows) return;
  const int beg = rp[row], end = rp[row + 1];
  float4 acc = {0.f, 0.f, 0.f, 0.f};
  int j = beg;
  for (; j + 3 < end; j += 4) {
    int c0 = col[j], c1 = col[j + 1], c2 = col[j + 2], c3 = col[j + 3];
    float4 v0 = src[(size_t)c0 * 32 + lane];
    float4 v1 = src[(size_t)c1 * 32 + lane];
    float4 v2 = src[(size_t)c2 * 32 + lane];
    float4 v3 = src[(size_t)c3 * 32 + lane];
    acc.x += (v0.x + v1.x) + (v2.x + v3.x);
    acc.y += (v0.y + v1.y) + (v2.y + v3.y);
    acc.z += (v0.z + v1.z) + (v2.z + v3.z);
    acc.w += (v0.w + v1.w) + (v2.w + v3.w);
  }
  for (; j < end; ++j) {
    int c = col[j];
    float4 v = src[(size_t)c * 32 + lane];
    acc.x += v.x;
    acc.y += v.y;
    acc.z += v.z;
    acc.w += v.w;
  }
  const float s = rscale[row];
  acc.x *= s;
  acc.y *= s;
  acc.z *= s;
  acc.w *= s;
  if (bias) {
    float4 b = bias[lane];
    acc.x += b.x;
    acc.y += b.y;
    acc.z += b.z;
    acc.w += b.w;
    if (relu) {
      acc.x = fmaxf(acc.x, 0.f);
      acc.y = fmaxf(acc.y, 0.f);
      acc.z = fmaxf(acc.z, 0.f);
      acc.w = fmaxf(acc.w, 0.f);
    }
  }
  dst[(size_t)row * 32 + lane] = acc;
}

extern "C" void kernel_launch(void* const* d_in, const int* in_sizes, int n_in,
                              void* d_out, int out_size, void* d_ws, size_t ws_size,
                              hipStream_t stream) {
  const float* x  = (const float*)d_in[0];
  const int* nidx = (const int*)d_in[1];
  const int nnz   = in_sizes[1] / 2;
  const int* eidx = nidx + nnz;
  const float* w  = (const float*)d_in[2];
  const float* W1 = (const float*)d_in[3];
  const float* b1 = (const float*)d_in[4];
  const float* W2 = (const float*)d_in[5];
  const float* b2 = (const float*)d_in[6];
  float* out = (float*)d_out;

  const int N = in_sizes[0] / 128;  // 65536 nodes
  const int E = in_sizes[2];        // 65536 edges
  const size_t NB = (size_t)N * 128;

  // workspace layout (4-byte units)
  float* f0      = (float*)d_ws;            // [N,128] feature buf A
  float* f1      = f0 + NB;                 // [N,128] feature buf B
  float* d_inv   = f1 + NB;                 // [N]
  float* e_scale = d_inv + N;               // [E]
  int* rp_e      = (int*)(e_scale + E);     // [E+1]
  int* rp_n      = rp_e + E + 1;            // [N+1]
  ushort16* col_e = (ushort16*)(rp_n + N + 1);  // [nnz]
  ushort16* col_n = col_e + nnz;                // [nnz]
  int* coarse_e  = (int*)(col_n + nnz);     // [257]
  int* coarse_n  = coarse_e + 257;          // [257]
  int* cur_e     = coarse_n + 257;          // [256]
  int* cur_n     = cur_e + 256;             // [256]
  // record buffers alias f0 (dead before first GEMM writes f0)
  uint32* rec_e  = (uint32*)f0;             // [nnz]
  uint32* rec_n  = rec_e + nnz;             // [nnz]

  const int gemm_grid = N / 128;
  const int ga_grid_e = (E * 32) / 256;
  const int ga_grid_n = (N * 32) / 256;

  // ---- CSR build (both sides) ----
  hipMemsetAsync(coarse_e, 0, (2 * 257 + 2 * 256) * sizeof(int), stream);
  k_passA<<<(nnz + 4095) / 4096, 256, 0, stream>>>(nidx, eidx, coarse_e, coarse_n, nnz);
  k_coarse_scan<<<1, 256, 0, stream>>>(coarse_e, coarse_e, cur_e, coarse_n, coarse_n, cur_n);
  k_passB<<<512, 256, 0, stream>>>(nidx, eidx, cur_e, cur_n, rec_e, rec_n, nnz);
  k_passC<<<512, 256, 0, stream>>>(rec_e, rec_n, coarse_e, coarse_n, w, rp_e, rp_n,
                                   col_e, col_n, e_scale, d_inv);

  // ---- layer 1 ----
  k_gemm<<<gemm_grid, 256, 0, stream>>>(x, W1, f0);  // f0 = x@W1 (kills recs)
  k_gather<<<ga_grid_e, 256, 0, stream>>>((const float4*)f0, (float4*)f1, rp_e, col_e,
                                          e_scale, nullptr, 0, E);           // f1 = e_feat
  k_gather<<<ga_grid_n, 256, 0, stream>>>((const float4*)f1, (float4*)f0, rp_n, col_n,
                                          d_inv, (const float4*)b1, 1, N);   // f0 = h

  // ---- layer 2 ----
  k_gemm<<<gemm_grid, 256, 0, stream>>>(f0, W2, f1);  // f1 = h@W2
  k_gather<<<ga_grid_e, 256, 0, stream>>>((const float4*)f1, (float4*)f0, rp_e, col_e,
                                          e_scale, nullptr, 0, E);           // f0 = e_feat
  k_gather<<<ga_grid_n, 256, 0, stream>>>((const float4*)f0, (float4*)out, rp_n, col_n,
                                          d_inv, (const float4*)b2, 0, N);   // out
}

// Round 5
// 322.975 us; speedup vs baseline: 22.6628x; 1.5771x over previous
//
#include <hip/hip_runtime.h>
#include <hip/hip_fp16.h>

// ---------------------------------------------------------------------------
// HypergraphNet: out = conv2(relu(conv1(x)))
// conv(x) = D^-1 H diag(w) B^-1 H^T (x @ W) + b
// N = E = 65536, F = 128, nnz = 2^20.
//
// Round-4: R3 (fp16 feature storage + MFMA f16 GEMM) with the B-stage LDS
// bug fixed: each thread copies 64 halves (8 x uint4), not 32. R3 left half
// of Bs uninitialized -> NaN.
//   k_prep_w     : W1,W2 -> half W^T [n][k] (once per call)
//   k_passA/B/C  : 2-level binned CSR build (unchanged from R2)
//   k_gemm<TA>   : MFMA 16x16x32_f16; A staged fp32->half or half; C half
//   k_gather     : 16 lanes x 16B(half8) per row, unroll-4, fused
//                  scale/bias/relu; half or fp32 output
// ---------------------------------------------------------------------------

typedef unsigned int uint32;
typedef unsigned short ushort16;
typedef _Float16 f16;
typedef _Float16 f16x8 __attribute__((ext_vector_type(8)));
typedef float f32x4 __attribute__((ext_vector_type(4)));

__global__ __launch_bounds__(256) void k_prep_w(const float* __restrict__ W1,
                                                const float* __restrict__ W2,
                                                f16* __restrict__ W1t,
                                                f16* __restrict__ W2t) {
  const float* W = (blockIdx.x & 1) ? W2 : W1;
  f16* Wt = (blockIdx.x & 1) ? W2t : W1t;
  const int base = (blockIdx.x >> 1) * 4096;
#pragma unroll
  for (int it = 0; it < 16; ++it) {
    int idx = base + it * 256 + threadIdx.x;
    int k = idx >> 7, n = idx & 127;
    Wt[n * 128 + k] = (f16)W[k * 128 + n];
  }
}

__global__ __launch_bounds__(256) void k_passA(const int* __restrict__ nidx,
                                               const int* __restrict__ eidx,
                                               int* __restrict__ coarse_e,
                                               int* __restrict__ coarse_n,
                                               int nnz) {
  __shared__ int he[256], hn[256];
  const int tid = threadIdx.x;
  he[tid] = 0;
  hn[tid] = 0;
  __syncthreads();
  const int base = blockIdx.x * 4096;
#pragma unroll
  for (int it = 0; it < 16; ++it) {
    int i = base + it * 256 + tid;
    if (i < nnz) {
      atomicAdd(&he[eidx[i] >> 8], 1);
      atomicAdd(&hn[nidx[i] >> 8], 1);
    }
  }
  __syncthreads();
  atomicAdd(&coarse_e[tid], he[tid]);
  atomicAdd(&coarse_n[tid], hn[tid]);
}

// One block. Exclusive-scan both 256-entry coarse count arrays; init cursors.
__global__ __launch_bounds__(256) void k_coarse_scan(const int* __restrict__ ce,
                                                     int* __restrict__ be,
                                                     int* __restrict__ cure,
                                                     const int* __restrict__ cn,
                                                     int* __restrict__ bn,
                                                     int* __restrict__ curn) {
  __shared__ int s[256];
  const int tid = threadIdx.x;
  int v = ce[tid];
  s[tid] = v;
  __syncthreads();
  for (int off = 1; off < 256; off <<= 1) {
    int t = (tid >= off) ? s[tid - off] : 0;
    __syncthreads();
    s[tid] += t;
    __syncthreads();
  }
  be[tid] = s[tid] - v;
  cure[tid] = s[tid] - v;
  if (tid == 255) be[256] = s[255];
  __syncthreads();
  v = cn[tid];
  s[tid] = v;
  __syncthreads();
  for (int off = 1; off < 256; off <<= 1) {
    int t = (tid >= off) ? s[tid - off] : 0;
    __syncthreads();
    s[tid] += t;
    __syncthreads();
  }
  bn[tid] = s[tid] - v;
  curn[tid] = s[tid] - v;
  if (tid == 255) bn[256] = s[255];
}

// Bin entries into coarse buckets as packed records (keylow<<16 | value).
__global__ __launch_bounds__(256) void k_passB(const int* __restrict__ nidx,
                                               const int* __restrict__ eidx,
                                               int* __restrict__ cur_e,
                                               int* __restrict__ cur_n,
                                               uint32* __restrict__ rec_e,
                                               uint32* __restrict__ rec_n,
                                               int nnz) {
  __shared__ int hist[256];
  __shared__ int gbase[256];
  __shared__ int lcur[256];
  const int tid = threadIdx.x;
  const int side = blockIdx.x >> 8;
  const int blk = blockIdx.x & 255;
  const int* keyp = side ? nidx : eidx;
  const int* valp = side ? eidx : nidx;
  int* cursor = side ? cur_n : cur_e;
  uint32* rec = side ? rec_n : rec_e;

  hist[tid] = 0;
  __syncthreads();
  int key[16], val[16];
  const int base = blk * 4096;
#pragma unroll
  for (int it = 0; it < 16; ++it) {
    int i = base + it * 256 + tid;
    if (i < nnz) {
      key[it] = keyp[i];
      val[it] = valp[i];
      atomicAdd(&hist[key[it] >> 8], 1);
    } else {
      key[it] = -1;
    }
  }
  __syncthreads();
  gbase[tid] = atomicAdd(&cursor[tid], hist[tid]);
  lcur[tid] = 0;
  __syncthreads();
#pragma unroll
  for (int it = 0; it < 16; ++it) {
    if (key[it] >= 0) {
      int d = key[it] >> 8;
      int p = atomicAdd(&lcur[d], 1);
      rec[gbase[d] + p] = ((uint32)(key[it] & 0xff) << 16) | (uint32)val[it];
    }
  }
}

// Finalize one coarse bucket: rp, scale, col.
__global__ __launch_bounds__(256) void k_passC(const uint32* __restrict__ rec_e,
                                               const uint32* __restrict__ rec_n,
                                               const int* __restrict__ be,
                                               const int* __restrict__ bn,
                                               const float* __restrict__ w,
                                               int* __restrict__ rp_e,
                                               int* __restrict__ rp_n,
                                               ushort16* __restrict__ col_e,
                                               ushort16* __restrict__ col_n,
                                               float* __restrict__ e_scale,
                                               float* __restrict__ d_inv) {
  __shared__ int hist[256];
  __shared__ int s[256];
  __shared__ int lcur[256];
  __shared__ float degf[256];
  const int tid = threadIdx.x;
  const int side = blockIdx.x >> 8;
  const int b = blockIdx.x & 255;
  const uint32* rec = side ? rec_n : rec_e;
  const int* bb = side ? bn : be;
  int* rp = side ? rp_n : rp_e;
  ushort16* col = side ? col_n : col_e;

  const int beg = bb[b], end = bb[b + 1];
  hist[tid] = 0;
  degf[tid] = 0.f;
  __syncthreads();
  for (int j = beg + tid; j < end; j += 256) {
    uint32 r = rec[j];
    int d = r >> 16;
    atomicAdd(&hist[d], 1);
    if (side) atomicAdd(&degf[d], w[r & 0xffff]);
  }
  __syncthreads();
  int h = hist[tid];
  s[tid] = h;
  __syncthreads();
  for (int off = 1; off < 256; off <<= 1) {
    int t = (tid >= off) ? s[tid - off] : 0;
    __syncthreads();
    s[tid] += t;
    __syncthreads();
  }
  const int start = s[tid] - h;
  const int key = (b << 8) | tid;
  rp[key] = beg + start;
  if (tid == 255) rp[(b << 8) + 256] = end;
  if (side) {
    float d = degf[tid];
    d_inv[key] = d > 0.f ? 1.f / d : 0.f;
  } else {
    e_scale[key] = h > 0 ? w[key] / (float)h : 0.f;
  }
  lcur[tid] = start;
  __syncthreads();
  for (int j = beg + tid; j < end; j += 256) {
    uint32 r = rec[j];
    int d = r >> 16;
    int p = atomicAdd(&lcur[d], 1);
    col[beg + p] = (ushort16)(r & 0xffff);
  }
}

// C[M,128] = A[M,128] @ B[128,128] via MFMA f16, C stored half.
// Bt is half W^T in [n][k] layout. Block: 64 M-rows, 4 waves, each a
// 32(M)x64(N) quadrant = 2x4 frags of 16x16, K unrolled 4x32.
template <typename TA>
__global__ __launch_bounds__(256) void k_gemm(const TA* __restrict__ A,
                                              const f16* __restrict__ Bt,
                                              f16* __restrict__ C) {
  __shared__ f16 As[64][136];   // stride 272B: 16B-aligned rows, ~2-way banks
  __shared__ f16 Bs[128][136];
  const int tid = threadIdx.x;
  const size_t m0 = (size_t)blockIdx.x * 64;

  {  // stage A: 4 threads/row, 32 halves each
    const int row = tid >> 2, seg = tid & 3;
    if constexpr (sizeof(TA) == 4) {
      const float4* ap = reinterpret_cast<const float4*>((const float*)A + (m0 + row) * 128 + seg * 32);
#pragma unroll
      for (int i = 0; i < 8; ++i) {
        float4 v = ap[i];
        union { f16 h[4]; uint2 u; } pk;
        pk.h[0] = (f16)v.x; pk.h[1] = (f16)v.y;
        pk.h[2] = (f16)v.z; pk.h[3] = (f16)v.w;
        *reinterpret_cast<uint2*>(&As[row][seg * 32 + i * 4]) = pk.u;
      }
    } else {
      const uint4* ap = reinterpret_cast<const uint4*>((const f16*)A + (m0 + row) * 128 + seg * 32);
#pragma unroll
      for (int i = 0; i < 4; ++i)
        *reinterpret_cast<uint4*>(&As[row][seg * 32 + i * 8]) = ap[i];
    }
  }
  {  // stage B: 2 threads/n-row, 64 halves each = 8 x uint4 (R3 bug: was 4)
    const int n = tid >> 1, seg = tid & 1;
    const uint4* bp = reinterpret_cast<const uint4*>(Bt + n * 128 + seg * 64);
#pragma unroll
    for (int i = 0; i < 8; ++i)
      *reinterpret_cast<uint4*>(&Bs[n][seg * 64 + i * 8]) = bp[i];
  }
  __syncthreads();

  const int wave = tid >> 6, lane = tid & 63;
  const int wm = wave >> 1, wn = wave & 1;
  const int fr = lane & 15, quad = lane >> 4;

  f32x4 acc[2][4];
#pragma unroll
  for (int i = 0; i < 2; ++i)
#pragma unroll
    for (int j = 0; j < 4; ++j) acc[i][j] = (f32x4){0.f, 0.f, 0.f, 0.f};

#pragma unroll
  for (int kk = 0; kk < 4; ++kk) {
    f16x8 af[2], bf[4];
#pragma unroll
    for (int i = 0; i < 2; ++i)
      af[i] = *reinterpret_cast<const f16x8*>(&As[wm * 32 + i * 16 + fr][kk * 32 + quad * 8]);
#pragma unroll
    for (int j = 0; j < 4; ++j)
      bf[j] = *reinterpret_cast<const f16x8*>(&Bs[wn * 64 + j * 16 + fr][kk * 32 + quad * 8]);
#pragma unroll
    for (int i = 0; i < 2; ++i)
#pragma unroll
      for (int j = 0; j < 4; ++j)
        acc[i][j] = __builtin_amdgcn_mfma_f32_16x16x32_f16(af[i], bf[j], acc[i][j], 0, 0, 0);
  }

  // C/D layout: col=lane&15, row=quad*4+reg (verified m89/m91)
#pragma unroll
  for (int i = 0; i < 2; ++i)
#pragma unroll
    for (int j = 0; j < 4; ++j)
#pragma unroll
      for (int r = 0; r < 4; ++r) {
        size_t row = m0 + wm * 32 + i * 16 + quad * 4 + r;
        int colc = wn * 64 + j * 16 + fr;
        C[row * 128 + colc] = (f16)acc[i][j][r];
      }
}

// 16 lanes x 16B (half8) per output row, unroll-4, fp32 accumulate.
// dst[row] = (sum_j src[col[j]]) * rscale[row] (+bias, relu); half or f32 out.
__global__ __launch_bounds__(256) void k_gather(const uint4* __restrict__ src,
                                                void* __restrict__ dst,
                                                const int* __restrict__ rp,
                                                const ushort16* __restrict__ col,
                                                const float* __restrict__ rscale,
                                                const float* __restrict__ bias,
                                                int relu, int out_f32, int nrows) {
  const int row = (blockIdx.x * 256 + threadIdx.x) >> 4;
  const int lane = threadIdx.x & 15;
  if (row >= nrows) return;
  const int beg = rp[row], end = rp[row + 1];
  float acc[8];
#pragma unroll
  for (int k = 0; k < 8; ++k) acc[k] = 0.f;
  union U { uint4 u; f16 h[8]; };
  int j = beg;
  for (; j + 3 < end; j += 4) {
    int c0 = col[j], c1 = col[j + 1], c2 = col[j + 2], c3 = col[j + 3];
    U v0, v1, v2, v3;
    v0.u = src[(size_t)c0 * 16 + lane];
    v1.u = src[(size_t)c1 * 16 + lane];
    v2.u = src[(size_t)c2 * 16 + lane];
    v3.u = src[(size_t)c3 * 16 + lane];
#pragma unroll
    for (int k = 0; k < 8; ++k)
      acc[k] += ((float)v0.h[k] + (float)v1.h[k]) + ((float)v2.h[k] + (float)v3.h[k]);
  }
  for (; j < end; ++j) {
    U v;
    v.u = src[(size_t)col[j] * 16 + lane];
#pragma unroll
    for (int k = 0; k < 8; ++k) acc[k] += (float)v.h[k];
  }
  const float s = rscale[row];
#pragma unroll
  for (int k = 0; k < 8; ++k) acc[k] *= s;
  if (bias) {
    const float4* bp = reinterpret_cast<const float4*>(bias) + lane * 2;
    float4 b0 = bp[0], b1 = bp[1];
    acc[0] += b0.x; acc[1] += b0.y; acc[2] += b0.z; acc[3] += b0.w;
    acc[4] += b1.x; acc[5] += b1.y; acc[6] += b1.z; acc[7] += b1.w;
    if (relu) {
#pragma unroll
      for (int k = 0; k < 8; ++k) acc[k] = fmaxf(acc[k], 0.f);
    }
  }
  if (out_f32) {
    float4* dp = (float4*)dst + (size_t)row * 32 + lane * 2;
    dp[0] = make_float4(acc[0], acc[1], acc[2], acc[3]);
    dp[1] = make_float4(acc[4], acc[5], acc[6], acc[7]);
  } else {
    U o;
#pragma unroll
    for (int k = 0; k < 8; ++k) o.h[k] = (f16)acc[k];
    ((uint4*)dst)[(size_t)row * 16 + lane] = o.u;
  }
}

extern "C" void kernel_launch(void* const* d_in, const int* in_sizes, int n_in,
                              void* d_out, int out_size, void* d_ws, size_t ws_size,
                              hipStream_t stream) {
  const float* x  = (const float*)d_in[0];
  const int* nidx = (const int*)d_in[1];
  const int nnz   = in_sizes[1] / 2;
  const int* eidx = nidx + nnz;
  const float* w  = (const float*)d_in[2];
  const float* W1 = (const float*)d_in[3];
  const float* b1 = (const float*)d_in[4];
  const float* W2 = (const float*)d_in[5];
  const float* b2 = (const float*)d_in[6];
  float* out = (float*)d_out;

  const int N = in_sizes[0] / 128;  // 65536 nodes
  const int E = in_sizes[2];        // 65536 edges
  const size_t NB = (size_t)N * 128;

  // workspace layout
  f16* f0h       = (f16*)d_ws;              // [N,128] half feature buf A
  f16* f1h       = f0h + NB;                // [N,128] half feature buf B
  float* d_inv   = (float*)(f1h + NB);      // [N]
  float* e_scale = d_inv + N;               // [E]
  int* rp_e      = (int*)(e_scale + E);     // [E+1]
  int* rp_n      = rp_e + E + 1;            // [N+1]
  ushort16* col_e = (ushort16*)(rp_n + N + 1);  // [nnz]
  ushort16* col_n = col_e + nnz;                // [nnz]
  int* coarse_e  = (int*)(col_n + nnz);     // [257]
  int* coarse_n  = coarse_e + 257;          // [257]
  int* cur_e     = coarse_n + 257;          // [256]
  int* cur_n     = cur_e + 256;             // [256]
  f16* W1t       = (f16*)(cur_n + 256);     // [128,128] half W1^T
  f16* W2t       = W1t + 128 * 128;         // [128,128] half W2^T
  // record buffers alias f0h (dead until GEMM-1 writes f0h)
  uint32* rec_e  = (uint32*)f0h;            // [nnz]
  uint32* rec_n  = rec_e + nnz;             // [nnz]

  const int gemm_grid = N / 64;
  const int ga_grid = (N * 16) / 256;  // N == E

  // ---- weight prep + CSR build ----
  k_prep_w<<<8, 256, 0, stream>>>(W1, W2, W1t, W2t);
  hipMemsetAsync(coarse_e, 0, (2 * 257 + 2 * 256) * sizeof(int), stream);
  k_passA<<<(nnz + 4095) / 4096, 256, 0, stream>>>(nidx, eidx, coarse_e, coarse_n, nnz);
  k_coarse_scan<<<1, 256, 0, stream>>>(coarse_e, coarse_e, cur_e, coarse_n, coarse_n, cur_n);
  k_passB<<<512, 256, 0, stream>>>(nidx, eidx, cur_e, cur_n, rec_e, rec_n, nnz);
  k_passC<<<512, 256, 0, stream>>>(rec_e, rec_n, coarse_e, coarse_n, w, rp_e, rp_n,
                                   col_e, col_n, e_scale, d_inv);

  // ---- layer 1 ----
  k_gemm<float><<<gemm_grid, 256, 0, stream>>>(x, W1t, f0h);   // f0h = half(x@W1)
  k_gather<<<ga_grid, 256, 0, stream>>>((const uint4*)f0h, f1h, rp_e, col_e,
                                        e_scale, nullptr, 0, 0, E);         // f1h = e_feat
  k_gather<<<ga_grid, 256, 0, stream>>>((const uint4*)f1h, f0h, rp_n, col_n,
                                        d_inv, b1, 1, 0, N);                // f0h = h

  // ---- layer 2 ----
  k_gemm<f16><<<gemm_grid, 256, 0, stream>>>(f0h, W2t, f1h);   // f1h = half(h@W2)
  k_gather<<<ga_grid, 256, 0, stream>>>((const uint4*)f1h, f0h, rp_e, col_e,
                                        e_scale, nullptr, 0, 0, E);         // f0h = e_feat
  k_gather<<<ga_grid, 256, 0, stream>>>((const uint4*)f0h, out, rp_n, col_n,
                                        d_inv, b2, 0, 1, N);                // out (fp32)
}